// Round 13
// baseline (544.266 us; speedup 1.0000x reference)
//
#include <hip/hip_runtime.h>
#include <stdint.h>

#define D_MODEL 1024
#define EXP_D   4096
#define NE      8
#define NTOK    8192
#define MAXT128H 144

typedef __attribute__((ext_vector_type(8))) short short8;
typedef __attribute__((ext_vector_type(4))) float f32x4;
typedef __attribute__((ext_vector_type(4))) unsigned short us4;

// ---- workspace layout (bytes) ----
#define WS_CURSORS   32         // int[8]
#define WS_PADOFF    64         // int[16]
#define WS_META      128        // int[32], meta[0]=nt (256-tiles), meta[1]=2*nt
#define WS_TILE_E    256        // int[960]
#define WS_PP        4096       // float[2048*8]
#define WS_TOP_E     69632      // int[16384]
#define WS_TOP_W     135168     // float[16384]
#define WS_TOK_RANK  200704     // int[16384]
#define WS_SLOT_W    270336     // float[18432]
#define WS_TOK_SLOT  344064     // int[16384]
#define WS_XG        409600     // bf16 18432 x 1024 (Yb aliases this) -> ends 38,158,336
#define WS_HB        38158336   // bf16 18432 x 4096 -> ends 189,153,280
#define WS_WB        189153280  // bf16 [8][4096][1024] -> ends 256,262,144
#define WS_WB2       256262144  // bf16 [8][1024][4096] (only if ws >= REQ_BIG2)
#define REQ_BIG2     323371008ull

__device__ __forceinline__ unsigned short f2bf(float f){
  __bf16 h = (__bf16)f;
  return __builtin_bit_cast(unsigned short, h);
}
__device__ __forceinline__ float bf2f(unsigned short u){
  unsigned int v = ((unsigned int)u) << 16;
  return __builtin_bit_cast(float, v);
}
__device__ __forceinline__ void gl_lds16(const void* g, void* l){
  __builtin_amdgcn_global_load_lds((const __attribute__((address_space(1))) unsigned int*)g,
                                   (__attribute__((address_space(3))) unsigned int*)l,
                                   16, 0, 0);
}

// ---------------- router (blocks 0..2047, NO atomics) + weight cvt (blocks >=2048) ----------------
__global__ __launch_bounds__(256) void router_cvt_kernel(
    const float* __restrict__ x, const float* __restrict__ Wr,
    const float* __restrict__ br,
    int* __restrict__ top_e, float* __restrict__ top_w,
    float* __restrict__ pp,
    const float* __restrict__ W1, unsigned short* __restrict__ Wb,
    const float* __restrict__ W2, unsigned short* __restrict__ W2b,
    int cvt_total4)
{
  const int tid = threadIdx.x;
  if ((int)blockIdx.x >= NTOK/4){
    const int n4 = NE*EXP_D*D_MODEL/4;
    const int stride = ((int)gridDim.x - NTOK/4)*256;
    for (int i = ((int)blockIdx.x - NTOK/4)*256 + tid; i < cvt_total4; i += stride){
      if (i < n4){
        const float4 v = *(const float4*)&W1[(size_t)i*4];
        us4 o; o[0]=f2bf(v.x); o[1]=f2bf(v.y); o[2]=f2bf(v.z); o[3]=f2bf(v.w);
        *(us4*)&Wb[(size_t)i*4] = o;
      } else {
        const int j = i - n4;
        const float4 v = *(const float4*)&W2[(size_t)j*4];
        us4 o; o[0]=f2bf(v.x); o[1]=f2bf(v.y); o[2]=f2bf(v.z); o[3]=f2bf(v.w);
        *(us4*)&W2b[(size_t)j*4] = o;
      }
    }
    return;
  }
  __shared__ float WrS[NE*D_MODEL];
  __shared__ float wprob[4][NE];
#pragma unroll
  for (int i=0;i<8;++i){
    int j = (tid + i*256)*4;
    *(float4*)&WrS[j] = *(const float4*)&Wr[j];
  }
  __syncthreads();
  const int w = tid>>6, lane = tid&63;
  const int t = blockIdx.x*4 + w;
  const float* xt = x + (size_t)t*D_MODEL;
  float accv[8] = {0,0,0,0,0,0,0,0};
#pragma unroll
  for (int i=0;i<4;++i){
    const int k = i*256 + lane*4;
    const float4 xv = *(const float4*)&xt[k];
#pragma unroll
    for (int e=0;e<8;++e){
      const float4 wv = *(const float4*)&WrS[e*D_MODEL + k];
      accv[e] += xv.x*wv.x + xv.y*wv.y + xv.z*wv.z + xv.w*wv.w;
    }
  }
#pragma unroll
  for (int m=32;m>0;m>>=1){
#pragma unroll
    for (int e=0;e<8;++e) accv[e] += __shfl_xor(accv[e], m, 64);
  }
  if (lane==0){
    float lg[8];
#pragma unroll
    for (int e=0;e<8;++e) lg[e] = accv[e] + br[e];
    float mx = lg[0];
#pragma unroll
    for (int e=1;e<8;++e) mx = fmaxf(mx, lg[e]);
    float p[8]; float s=0.f;
#pragma unroll
    for (int e=0;e<8;++e){ p[e] = __expf(lg[e]-mx); s += p[e]; }
    const float inv = 1.f/s;
#pragma unroll
    for (int e=0;e<8;++e){ p[e] *= inv; wprob[w][e] = p[e]; }
    int i1=0; float p1v=p[0];
#pragma unroll
    for (int e=1;e<8;++e) if (p[e] > p1v){ p1v=p[e]; i1=e; }
    int i2=-1; float p2v=-1.f;
#pragma unroll
    for (int e=0;e<8;++e) if (e!=i1 && p[e] > p2v){ p2v=p[e]; i2=e; }
    const float rn = 1.f/(p1v+p2v);
    top_e[2*t]   = i1; top_w[2*t]   = p1v*rn;
    top_e[2*t+1] = i2; top_w[2*t+1] = p2v*rn;
  }
  __syncthreads();
  if (tid<8){
    pp[blockIdx.x*8+tid] = wprob[0][tid]+wprob[1][tid]+wprob[2][tid]+wprob[3][tid];
  }
}

// ---------------- standalone cvt (fallback, W2) ----------------
__global__ __launch_bounds__(256) void cvt_kernel(const float* __restrict__ W,
                                                  unsigned short* __restrict__ Wb){
  const int n4 = NE*EXP_D*D_MODEL/4;
  for (int i = blockIdx.x*256 + threadIdx.x; i < n4; i += gridDim.x*256){
    const float4 v = *(const float4*)&W[(size_t)i*4];
    us4 o; o[0]=f2bf(v.x); o[1]=f2bf(v.y); o[2]=f2bf(v.z); o[3]=f2bf(v.w);
    *(us4*)&Wb[(size_t)i*4] = o;
  }
}

// ---------------- scatter: LDS-aggregated counting + expert-local ranks ----------------
__global__ __launch_bounds__(1024) void scatter_kernel(
    const int* __restrict__ top_e,
    int* __restrict__ cursors, int* __restrict__ tok_rank)
{
  __shared__ int cnt[NE];
  __shared__ int base[NE];
  const int tid = threadIdx.x;
  if (tid < NE) cnt[tid] = 0;
  __syncthreads();
  const int t = blockIdx.x*1024 + tid;
  const int e0 = top_e[2*t], e1 = top_e[2*t+1];
  const int p0 = atomicAdd(&cnt[e0], 1);
  const int p1 = atomicAdd(&cnt[e1], 1);
  __syncthreads();
  if (tid < NE) base[tid] = atomicAdd(&cursors[tid], cnt[tid]);
  __syncthreads();
  tok_rank[2*t]   = base[e0] + p0;
  tok_rank[2*t+1] = base[e1] + p1;
}

// ---------------- prefix (AFTER scatter): tile table (256-pad) + aux ----------------
__global__ __launch_bounds__(256) void prefix_kernel(int* __restrict__ wsI,
                                                     const float* __restrict__ pp,
                                                     float* __restrict__ aux_out){
  const int tid = threadIdx.x;
  int* counts = wsI + 8;
  int* padoff = wsI + 16;
  int* meta   = wsI + 32;
  int* tileE  = wsI + 64;
  __shared__ int tileCum[9];
  __shared__ float dev2[8];
  if (tid==0){
    int nt = 0;
    tileCum[0] = 0;
    for (int e=0;e<NE;++e){
      padoff[e] = nt << 8;
      nt += (counts[e] + 255) >> 8;
      tileCum[e+1] = nt;
    }
    meta[0] = nt;
    meta[1] = 2*nt;
  }
  __syncthreads();
  const int nt = tileCum[8];
  for (int i=tid; i<nt; i+=256){
    int e = 0;
    while (tileCum[e+1] <= i) ++e;
    tileE[i] = e;
  }
  const int ex = tid>>5, j = tid&31;
  float s = 0.f;
  for (int b=j; b<NTOK/4; b+=32) s += pp[b*8+ex];
#pragma unroll
  for (int m=16;m>0;m>>=1) s += __shfl_xor(s, m, 64);
  if (j==0){ float d = s*(1.f/(float)NTOK) - 0.125f; dev2[ex] = d*d; }
  __syncthreads();
  if (tid==0){
    float a=0.f;
#pragma unroll
    for (int e=0;e<8;++e) a += dev2[e];
    aux_out[0] = a;
  }
}

// ---------------- gather: slot = padoff[e] + rank; write tok_slot/slot_w/Xg rows ----------------
__global__ __launch_bounds__(256) void gather_kernel(
    const float* __restrict__ x, const int* __restrict__ top_e,
    const float* __restrict__ top_w, const int* __restrict__ tok_rank,
    const int* __restrict__ padoff,
    int* __restrict__ tok_slot, float* __restrict__ slot_w,
    unsigned short* __restrict__ Xg)
{
  const int w = threadIdx.x>>6, lane = threadIdx.x&63;
  const int t = blockIdx.x*4 + w;
  const int s0 = padoff[top_e[2*t]]   + tok_rank[2*t];
  const int s1 = padoff[top_e[2*t+1]] + tok_rank[2*t+1];
  if (lane==0){
    tok_slot[2*t] = s0; tok_slot[2*t+1] = s1;
    slot_w[s0] = top_w[2*t]; slot_w[s1] = top_w[2*t+1];
  }
  us4 o[4];
#pragma unroll
  for (int i=0;i<4;++i){
    const float4 v = *(const float4*)&x[(size_t)t*D_MODEL + i*256 + lane*4];
    o[i][0]=f2bf(v.x); o[i][1]=f2bf(v.y); o[i][2]=f2bf(v.z); o[i][3]=f2bf(v.w);
  }
#pragma unroll
  for (int i=0;i<4;++i) *(us4*)&Xg[(size_t)s0*D_MODEL + i*256 + lane*4] = o[i];
#pragma unroll
  for (int i=0;i<4;++i) *(us4*)&Xg[(size_t)s1*D_MODEL + i*256 + lane*4] = o[i];
}

// ============ TLP GEMM: 128x128 tile, BK=64, 8 waves (32x64/wave), 2-buf 64KB, 2 blocks/CU ============
// Plain m97-style loop: gl_lds staging + compiler-scheduled ds_reads/MFMA + one __syncthreads
// per K-tile (drains vmcnt+lgkm). Conflict-free swizzle: chunk ^= row&7 (both sides).
// C[m][n] = sum_k A[m][k] * W[e][n][k]  (+bias; G1: relu; G2: *slot_w[m])
template<int KT, int NT, bool G2>
__global__ __launch_bounds__(512,4) void moe_tlp(
    const unsigned short* __restrict__ A,
    const unsigned short* __restrict__ Wb,
    const float* __restrict__ bias,
    unsigned short* __restrict__ Cout,
    const int* __restrict__ tileE,
    const int* __restrict__ meta,
    const float* __restrict__ slotw)
{
  constexpr int NX = NT/128;
  constexpr int TOTAL = NX*MAXT128H;
  constexpr int Q = TOTAL/8, R = TOTAL%8;
  constexpr int NTILES = KT/64;

  const int lid = blockIdx.x;
  const int xcc = lid & 7, jj = lid >> 3;
  const int tsw = xcc*Q + (xcc < R ? xcc : R) + jj;
  const int mtile = tsw / NX, ntile = tsw - mtile*NX;
  if (mtile >= meta[1]) return;

  extern __shared__ char smem[];
  char* const BUF0 = smem;
  char* const BUF1 = smem + 32768;

  const int tid = threadIdx.x;
  const int w = tid>>6, lane = tid&63;
  const int wr = w>>1, wn = w&1;
  const int r15 = lane&15, kg = lane>>4;
  const int e  = tileE[mtile>>1];
  const int m0 = mtile*128;
  const int n0 = ntile*128;

  // staging (pre-swizzled global chunk; LDS dest linear). Buffer: A 16KB @0, B 16KB @16384.
  const int trow = tid>>3;                     // 0..63
  const int tch  = ((tid&7) ^ (trow&7))*8;     // elements
  const unsigned short* sA = A  + (size_t)(m0 + trow)*KT + tch;
  const unsigned short* sB = Wb + (size_t)e*NT*KT + (size_t)(n0 + trow)*KT + tch;

#define STG(BS, KTT) do{ \
    gl_lds16(sA + (size_t)(KTT)*64,                 (BS) + tid*16); \
    gl_lds16(sA + (size_t)(KTT)*64 + (size_t)64*KT, (BS) + 8192  + tid*16); \
    gl_lds16(sB + (size_t)(KTT)*64,                 (BS) + 16384 + tid*16); \
    gl_lds16(sB + (size_t)(KTT)*64 + (size_t)64*KT, (BS) + 24576 + tid*16); \
  }while(0)

  // fragment read byte-offsets (ks=0); ks=1 -> ^64 (chunk ^= 4)
  const int key = (kg ^ (r15&7))<<4;
  const int a0o = (wr*32 +  0 + r15)*128 + key;
  const int a1o = (wr*32 + 16 + r15)*128 + key;
  const int b0o = 16384 + (wn*64 +  0 + r15)*128 + key;
  const int b1o = 16384 + (wn*64 + 16 + r15)*128 + key;
  const int b2o = 16384 + (wn*64 + 32 + r15)*128 + key;
  const int b3o = 16384 + (wn*64 + 48 + r15)*128 + key;

  f32x4 acc[2][4];
#pragma unroll
  for (int i=0;i<2;++i)
#pragma unroll
    for (int j=0;j<4;++j) acc[i][j] = (f32x4){0.f,0.f,0.f,0.f};

  // prologue
  STG(BUF0, 0);
  __syncthreads();

#pragma unroll 1
  for (int t = 0; t < NTILES; ++t){
    const char* BC = (t&1) ? BUF1 : BUF0;
    if (t+1 < NTILES){
      char* BS = (t&1) ? BUF0 : BUF1;
      STG(BS, t+1);
    }
#pragma unroll
    for (int ks = 0; ks < 2; ++ks){
      const int x = ks*64;
      const short8 af0 = *(const short8*)(BC + (a0o ^ x));
      const short8 af1 = *(const short8*)(BC + (a1o ^ x));
      const short8 bv0 = *(const short8*)(BC + (b0o ^ x));
      const short8 bv1 = *(const short8*)(BC + (b1o ^ x));
      const short8 bv2 = *(const short8*)(BC + (b2o ^ x));
      const short8 bv3 = *(const short8*)(BC + (b3o ^ x));
      acc[0][0]=__builtin_amdgcn_mfma_f32_16x16x32_bf16(bv0,af0,acc[0][0],0,0,0);
      acc[0][1]=__builtin_amdgcn_mfma_f32_16x16x32_bf16(bv1,af0,acc[0][1],0,0,0);
      acc[0][2]=__builtin_amdgcn_mfma_f32_16x16x32_bf16(bv2,af0,acc[0][2],0,0,0);
      acc[0][3]=__builtin_amdgcn_mfma_f32_16x16x32_bf16(bv3,af0,acc[0][3],0,0,0);
      acc[1][0]=__builtin_amdgcn_mfma_f32_16x16x32_bf16(bv0,af1,acc[1][0],0,0,0);
      acc[1][1]=__builtin_amdgcn_mfma_f32_16x16x32_bf16(bv1,af1,acc[1][1],0,0,0);
      acc[1][2]=__builtin_amdgcn_mfma_f32_16x16x32_bf16(bv2,af1,acc[1][2],0,0,0);
      acc[1][3]=__builtin_amdgcn_mfma_f32_16x16x32_bf16(bv3,af1,acc[1][3],0,0,0);
    }
    __syncthreads();   // drains vmcnt (stage t+1 landed) + lgkm; 2-buf invariant holds
  }
#undef STG

  // epilogue: m = m0 + wr*32 + mf*16 + r15; n = n0 + wn*64 + nf*16 + kg*4
  const int ng4 = kg*4;
#pragma unroll
  for (int mf=0; mf<2; ++mf){
    const int m = m0 + wr*32 + mf*16 + r15;
    float wg = 0.f;
    if (G2) wg = slotw[m];
#pragma unroll
    for (int nf=0; nf<4; ++nf){
      const int nb = n0 + wn*64 + nf*16 + ng4;
      const float4 bv = *(const float4*)&bias[(size_t)e*NT + nb];
      float q0 = acc[mf][nf][0] + bv.x;
      float q1 = acc[mf][nf][1] + bv.y;
      float q2 = acc[mf][nf][2] + bv.z;
      float q3 = acc[mf][nf][3] + bv.w;
      if (!G2){
        q0=fmaxf(q0,0.f); q1=fmaxf(q1,0.f); q2=fmaxf(q2,0.f); q3=fmaxf(q3,0.f);
      } else {
        q0*=wg; q1*=wg; q2*=wg; q3*=wg;
      }
      us4 o; o[0]=f2bf(q0); o[1]=f2bf(q1); o[2]=f2bf(q2); o[3]=f2bf(q3);
      *(us4*)&Cout[(size_t)m*NT + nb] = o;
    }
  }
}

// ---------------- combine: out[t] = Y[slot0] + Y[slot1] ----------------
__global__ __launch_bounds__(256) void combine_kernel(
    const unsigned short* __restrict__ Yb, const int* __restrict__ tok_slot,
    float* __restrict__ out)
{
  const int t = blockIdx.x;
  const int tid = threadIdx.x;
  const int s0 = tok_slot[2*t], s1 = tok_slot[2*t+1];
  const us4 a = *(const us4*)&Yb[(size_t)s0*D_MODEL + tid*4];
  const us4 b = *(const us4*)&Yb[(size_t)s1*D_MODEL + tid*4];
  float4 o;
  o.x = bf2f(a[0]) + bf2f(b[0]);
  o.y = bf2f(a[1]) + bf2f(b[1]);
  o.z = bf2f(a[2]) + bf2f(b[2]);
  o.w = bf2f(a[3]) + bf2f(b[3]);
  *(float4*)&out[(size_t)t*D_MODEL + tid*4] = o;
}

extern "C" void kernel_launch(void* const* d_in, const int* in_sizes, int n_in,
                              void* d_out, int out_size, void* d_ws, size_t ws_size,
                              hipStream_t stream)
{
  const float* x  = (const float*)d_in[0];
  const float* Wr = (const float*)d_in[1];
  const float* br = (const float*)d_in[2];
  const float* W1 = (const float*)d_in[3];
  const float* b1 = (const float*)d_in[4];
  const float* W2 = (const float*)d_in[5];
  const float* b2 = (const float*)d_in[6];
  float* out = (float*)d_out;
  char* ws = (char*)d_ws;

  const bool fusedcvt = ws_size >= REQ_BIG2;

  int*   cursors = (int*)(ws + WS_CURSORS);
  int*   padoff  = (int*)(ws + WS_PADOFF);
  int*   meta    = (int*)(ws + WS_META);
  int*   tileE   = (int*)(ws + WS_TILE_E);
  float* pp      = (float*)(ws + WS_PP);
  int*   top_e   = (int*)(ws + WS_TOP_E);
  float* top_w   = (float*)(ws + WS_TOP_W);
  int*   tok_rank= (int*)(ws + WS_TOK_RANK);
  float* slot_w  = (float*)(ws + WS_SLOT_W);
  int*   tok_slot= (int*)(ws + WS_TOK_SLOT);
  unsigned short* Xg  = (unsigned short*)(ws + WS_XG);
  unsigned short* Hb  = (unsigned short*)(ws + WS_HB);
  unsigned short* Wb  = (unsigned short*)(ws + WS_WB);
  unsigned short* W2b = (unsigned short*)(ws + WS_WB2);
  unsigned short* Yb  = Xg;   // Xg dead after GEMM1

  hipFuncSetAttribute((const void*)moe_tlp<D_MODEL, EXP_D, false>,
                      hipFuncAttributeMaxDynamicSharedMemorySize, 65536);
  hipFuncSetAttribute((const void*)moe_tlp<EXP_D, D_MODEL, true>,
                      hipFuncAttributeMaxDynamicSharedMemorySize, 65536);

  const int n4 = NE*EXP_D*D_MODEL/4;
  hipMemsetAsync(ws, 0, 128, stream);   // cursors zero
  if (fusedcvt){
    router_cvt_kernel<<<dim3(NTOK/4 + 4096), dim3(256), 0, stream>>>(
        x, Wr, br, top_e, top_w, pp, W1, Wb, W2, W2b, 2*n4);
  } else {
    router_cvt_kernel<<<dim3(NTOK/4 + 2048), dim3(256), 0, stream>>>(
        x, Wr, br, top_e, top_w, pp, W1, Wb, W2, Wb, n4);
  }
  scatter_kernel<<<dim3(NTOK/1024), dim3(1024), 0, stream>>>(top_e, cursors, tok_rank);
  prefix_kernel<<<dim3(1), dim3(256), 0, stream>>>((int*)ws, pp, out + (size_t)NTOK*D_MODEL);
  gather_kernel<<<dim3(NTOK/4), dim3(256), 0, stream>>>(x, top_e, top_w, tok_rank, padoff,
                                                        tok_slot, slot_w, Xg);
  moe_tlp<D_MODEL, EXP_D, false>
      <<<dim3((EXP_D/128)*MAXT128H), dim3(512), 65536, stream>>>(
      Xg, Wb, b1, Hb, tileE, meta, slot_w);
  if (!fusedcvt){
    cvt_kernel<<<dim3(2048), dim3(256), 0, stream>>>(W2, Wb);
  }
  moe_tlp<EXP_D, D_MODEL, true>
      <<<dim3((D_MODEL/128)*MAXT128H), dim3(512), 65536, stream>>>(
      Hb, fusedcvt ? W2b : Wb, b2, Yb, tileE, meta, slot_w);
  combine_kernel<<<dim3(NTOK), dim3(256), 0, stream>>>(Yb, tok_slot, out);
}